// Round 10
// baseline (398.165 us; speedup 1.0000x reference)
//
#include <hip/hip_runtime.h>
#include <hip/hip_bf16.h>

// ---------- problem constants ----------
constexpr int Nrows = 8192;   // batch rows
constexpr int L     = 256;    // input_len / features
constexpr int D     = 128;    // hidden per head
constexpr float EPS = 1e-5f;

typedef __bf16 bf16x8 __attribute__((ext_vector_type(8)));
typedef __bf16 bf16x4 __attribute__((ext_vector_type(4)));
typedef float  f32x4  __attribute__((ext_vector_type(4)));

#define MFMA16(a, b, c) __builtin_amdgcn_mfma_f32_16x16x32_bf16((a), (b), (c), 0, 0, 0)

// ============================================================
// param convert+transpose (fp32 -> bf16):
//   Bt[6][128][256]: Bt[g][d][l] = P_g[l*128+d], P_g in {Q0,K0,Vd0,Q1,K1,Vd1}
//   VupT[2][256][128]: VupT[h][l][d] = Vup[h][d][l]
//   Wb[2][256][256]: straight bf16 copy of W
// ============================================================
__global__ void k_cvt_params(const float* __restrict__ Q, const float* __restrict__ K,
                             const float* __restrict__ Vd, const float* __restrict__ Vup,
                             const float* __restrict__ W,
                             __bf16* __restrict__ Bt, __bf16* __restrict__ VupT,
                             __bf16* __restrict__ Wb) {
    int i = blockIdx.x * 256 + threadIdx.x;
    if (i < 6 * 128 * 256) {
        int g = i >> 15; int r = i & 32767; int d = r >> 8; int l = r & 255;
        const float* src = (g % 3 == 0 ? Q : (g % 3 == 1 ? K : Vd)) + (g / 3) * (L * D);
        Bt[i] = (__bf16)src[l * D + d];
    } else if (i < 8 * 128 * 256) {
        int j = i - 6 * 128 * 256;               // [0, 65536)
        int h = j >> 15; int r = j & 32767; int l = r >> 7; int d = r & 127;
        VupT[j] = (__bf16)Vup[h * (D * L) + d * L + l];
    } else {
        int j = i - 8 * 128 * 256;               // [0, 131072)
        Wb[j] = (__bf16)W[j];
    }
}

// ============================================================
// batchnorm stats for x: per-column sum / sumsq (256 blocks x 32 rows)
// ============================================================
__global__ void k_bn_stats(const float* __restrict__ x, float* __restrict__ sum,
                           float* __restrict__ sq) {
    int col = threadIdx.x;                        // 256 columns
    int r0 = blockIdx.x * 32;                     // 256 blocks x 32 rows
    float s = 0.f, s2 = 0.f;
    for (int i = 0; i < 32; i++) {
        float v = x[(r0 + i) * L + col];
        s += v; s2 += v * v;
    }
    atomicAdd(&sum[col], s);
    atomicAdd(&sq[col], s2);
}

// ============================================================
// batchnorm normalize: bn1 emits bf16 (for GEMMs) + fp32 (residual)
// ============================================================
__global__ void k_bn_norm1(const float* __restrict__ x, const float* __restrict__ sum,
                           const float* __restrict__ sq, __bf16* __restrict__ hb,
                           float* __restrict__ hf) {
    int i = (blockIdx.x * 256 + threadIdx.x) * 4;
    int col = i & (L - 1);
    f32x4 v = *(const f32x4*)(x + i);
    bf16x4 o; f32x4 of;
#pragma unroll
    for (int j = 0; j < 4; j++) {
        float m   = sum[col + j] * (1.0f / Nrows);
        float var = sq[col + j] * (1.0f / Nrows) - m * m;
        float rs  = rsqrtf(var + EPS);
        float t = (v[j] - m) * rs;
        of[j] = t; o[j] = (__bf16)t;
    }
    *(bf16x4*)(hb + i) = o;
    *(f32x4*)(hf + i) = of;
}

// ============================================================
// QKV projection: 64-row tiles, grid (128, 6) = 768 blocks (3/CU even)
// q/k row-major [8192][128]; v TRANSPOSED Vt[head][128][8192]
// ============================================================
__launch_bounds__(256)
__global__ void k_gemm_qkv(const __bf16* __restrict__ h, const __bf16* __restrict__ Bt,
                           __bf16* __restrict__ q0, __bf16* __restrict__ k0,
                           __bf16* __restrict__ q1, __bf16* __restrict__ k1,
                           __bf16* __restrict__ Vt) {
    int g = blockIdx.y;                 // 0..5
    int m0 = blockIdx.x * 64;
    int w = threadIdx.x >> 6, lane = threadIdx.x & 63;
    int c = lane & 15, qd = lane >> 4;
    int mw = m0 + w * 16;
    const __bf16* B = Bt + g * (128 * 256);

    f32x4 acc[8] = {};
#pragma unroll
    for (int kc = 0; kc < 8; kc++) {
        bf16x8 a = *(const bf16x8*)(h + (mw + c) * L + kc * 32 + qd * 8);
#pragma unroll
        for (int nt = 0; nt < 8; nt++) {
            bf16x8 b = *(const bf16x8*)(B + (nt * 16 + c) * L + kc * 32 + qd * 8);
            acc[nt] = MFMA16(a, b, acc[nt]);
        }
    }
    if (g == 2 || g == 5) {
        __bf16* vt = Vt + (g / 3) * (128 * Nrows);
#pragma unroll
        for (int nt = 0; nt < 8; nt++)
#pragma unroll
            for (int r = 0; r < 4; r++) {
                int row = mw + 4 * qd + r;         // n (sequence) index
                int colv = nt * 16 + c;            // d index
                vt[colv * Nrows + row] = (__bf16)acc[nt][r];
            }
    } else {
        __bf16* dst = (g == 0) ? q0 : (g == 1) ? k0 : (g == 3) ? q1 : k1;
#pragma unroll
        for (int nt = 0; nt < 8; nt++)
#pragma unroll
            for (int r = 0; r < 4; r++) {
                int row = mw + 4 * qd + r;
                int colv = nt * 16 + c;
                dst[row * D + colv] = (__bf16)acc[nt][r];
            }
    }
}

// ============================================================
// Flash attention: 32 Q rows/block, 512 blocks = 2 blocks/CU (TLP), with
// r3's register K-prefetch. __launch_bounds__(256,2): 2 blocks x 4 waves
// = 2 waves/SIMD -> 256-VGPR cap; live set ~200 (aq16+oacc32+Kdbuf64+
// V32+lp8+temps) fits -> no spill (r4/r5/r8 spill mechanism avoided).
// Two co-resident blocks interleave the serial QK->exp->LDS->PV chains.
// V single-buffered to protect the register margin.
// ============================================================
__launch_bounds__(256, 2)
__global__ void k_flash(const __bf16* __restrict__ q0, const __bf16* __restrict__ k0,
                        const __bf16* __restrict__ q1, const __bf16* __restrict__ k1,
                        const __bf16* __restrict__ Vt, __bf16* __restrict__ O) {
    int head = blockIdx.x & 1;
    int qtile = blockIdx.x >> 1;       // 0..255
    int m0 = qtile * 32;
    const __bf16* qm = head ? q1 : q0;
    const __bf16* km = head ? k1 : k0;
    const __bf16* vt = Vt + head * (128 * Nrows);
    __bf16* Og = O + head * (Nrows * D);

    int w = threadIdx.x >> 6, lane = threadIdx.x & 63;
    int c = lane & 15, qd = lane >> 4;

    __shared__ __bf16 Pb[4][32 * 56];     // stride 56 => 16B-aligned rows
    __shared__ float l_red[4][32];
    __shared__ float l_inv[32];
    __shared__ float obuf[4][32][16];

    bf16x8 aq[2][4];
#pragma unroll
    for (int mt = 0; mt < 2; mt++)
#pragma unroll
        for (int kc = 0; kc < 4; kc++)
            aq[mt][kc] = *(const bf16x8*)(qm + (m0 + mt * 16 + c) * D + kc * 32 + qd * 8);

    f32x4 oacc[2][8] = {};
    float lp[2][4] = {};
    __bf16* Pw = &Pb[w][0];

    auto loadk = [&](bf16x8 (&kb)[2][4], int n0) {
        int nb = n0 + w * 32;            // this wave's key slice
#pragma unroll
        for (int nt = 0; nt < 2; nt++)
#pragma unroll
            for (int kc = 0; kc < 4; kc++)
                kb[nt][kc] = *(const bf16x8*)(km + (nb + nt * 16 + c) * D + kc * 32 + qd * 8);
    };
    auto loadv = [&](bf16x8 (&vb)[8], int n0) {
        int nb = n0 + w * 32;
#pragma unroll
        for (int dvt = 0; dvt < 8; dvt++)
            vb[dvt] = *(const bf16x8*)(vt + (dvt * 16 + c) * Nrows + nb + qd * 8);
    };
    auto compute = [&](const bf16x8 (&kb)[2][4], const bf16x8 (&vb)[8]) {
#pragma unroll
        for (int nt = 0; nt < 2; nt++) {
            f32x4 s[2] = {};
            __builtin_amdgcn_s_setprio(1);
#pragma unroll
            for (int kc = 0; kc < 4; kc++) {
#pragma unroll
                for (int mt = 0; mt < 2; mt++) s[mt] = MFMA16(aq[mt][kc], kb[nt][kc], s[mt]);
            }
            __builtin_amdgcn_s_setprio(0);
#pragma unroll
            for (int mt = 0; mt < 2; mt++)
#pragma unroll
                for (int r = 0; r < 4; r++) {
                    float e = __expf(s[mt][r]);
                    lp[mt][r] += e;
                    Pw[(mt * 16 + 4 * qd + r) * 56 + nt * 16 + c] = (__bf16)e;
                }
        }
        bf16x8 ap[2];
#pragma unroll
        for (int mt = 0; mt < 2; mt++)
            ap[mt] = *(const bf16x8*)(Pw + (mt * 16 + c) * 56 + qd * 8);
        __builtin_amdgcn_s_setprio(1);
#pragma unroll
        for (int dvt = 0; dvt < 8; dvt++) {
#pragma unroll
            for (int mt = 0; mt < 2; mt++) oacc[mt][dvt] = MFMA16(ap[mt], vb[dvt], oacc[mt][dvt]);
        }
        __builtin_amdgcn_s_setprio(0);
    };

    bf16x8 kbA[2][4], kbB[2][4], vb[8];
    loadk(kbA, 0);
    for (int n0 = 0; n0 < Nrows; n0 += 256) {
        loadk(kbB, n0 + 128);            // prefetch next K tile
        loadv(vb, n0);                   // V for current tile
        compute(kbA, vb);
        if (n0 + 256 < Nrows) loadk(kbA, n0 + 256);
        loadv(vb, n0 + 128);
        compute(kbB, vb);
    }

#pragma unroll
    for (int mt = 0; mt < 2; mt++)
#pragma unroll
        for (int r = 0; r < 4; r++) {
            float v = lp[mt][r];
            v += __shfl_xor(v, 1, 16);
            v += __shfl_xor(v, 2, 16);
            v += __shfl_xor(v, 4, 16);
            v += __shfl_xor(v, 8, 16);
            lp[mt][r] = v;
        }
    if (c == 0) {
#pragma unroll
        for (int mt = 0; mt < 2; mt++)
#pragma unroll
            for (int r = 0; r < 4; r++)
                l_red[w][mt * 16 + 4 * qd + r] = lp[mt][r];
    }
    __syncthreads();
    if (threadIdx.x < 32)
        l_inv[threadIdx.x] = 1.0f / (l_red[0][threadIdx.x] + l_red[1][threadIdx.x] +
                                     l_red[2][threadIdx.x] + l_red[3][threadIdx.x]);

    for (int dvt = 0; dvt < 8; dvt++) {
        __syncthreads();
#pragma unroll
        for (int mt = 0; mt < 2; mt++)
#pragma unroll
            for (int r = 0; r < 4; r++)
                obuf[w][mt * 16 + 4 * qd + r][c] = oacc[mt][dvt][r];
        __syncthreads();
        int t = threadIdx.x;
        if (t < 128) {
            int row = t >> 2;            // 0..31
            int col = (t & 3) * 4;       // 0,4,8,12
            f32x4 v = *(const f32x4*)&obuf[0][row][col];
            f32x4 v1 = *(const f32x4*)&obuf[1][row][col];
            f32x4 v2 = *(const f32x4*)&obuf[2][row][col];
            f32x4 v3 = *(const f32x4*)&obuf[3][row][col];
            float il = l_inv[row];
            bf16x4 o;
#pragma unroll
            for (int e = 0; e < 4; e++) o[e] = (__bf16)((v[e] + v1[e] + v2[e] + v3[e]) * il);
            *(bf16x4*)(Og + (m0 + row) * D + dvt * 16 + col) = o;
        }
    }
}

// ============================================================
// z = hf + O0 @ Vup0 + O1 @ Vup1  (fp32 out) with FUSED bn-stats of z:
// per-wave shfl reduction over its 16 rows, one atomicAdd per column.
// Removes the separate 8 MB bn_stats(z) pass + launch.
// 64-row tiles, grid (128, 2) = 256 blocks (1/CU)
// ============================================================
__launch_bounds__(256)
__global__ void k_gemm_vup(const __bf16* __restrict__ O, const __bf16* __restrict__ VupT,
                           const float* __restrict__ hf, float* __restrict__ z,
                           float* __restrict__ sum2, float* __restrict__ sq2) {
    int n0 = blockIdx.y * 128;
    int m0 = blockIdx.x * 64;
    int w = threadIdx.x >> 6, lane = threadIdx.x & 63;
    int c = lane & 15, qd = lane >> 4;
    int mw = m0 + w * 16;

    f32x4 acc[8] = {};
#pragma unroll
    for (int kc = 0; kc < 8; kc++) {
        const __bf16* Oh = O + (kc >> 2) * (Nrows * D);
        const __bf16* Vh = VupT + (kc >> 2) * (L * D);
        int ko = (kc & 3) * 32 + qd * 8;
        bf16x8 a = *(const bf16x8*)(Oh + (mw + c) * D + ko);
#pragma unroll
        for (int nt = 0; nt < 8; nt++) {
            bf16x8 b = *(const bf16x8*)(Vh + (n0 + nt * 16 + c) * D + ko);
            acc[nt] = MFMA16(a, b, acc[nt]);
        }
    }
#pragma unroll
    for (int nt = 0; nt < 8; nt++) {
        int col = n0 + nt * 16 + c;
        float s = 0.f, s2 = 0.f;
#pragma unroll
        for (int r = 0; r < 4; r++) {
            int row = mw + 4 * qd + r;
            float zv = acc[nt][r] + hf[row * L + col];
            z[row * L + col] = zv;
            s += zv; s2 += zv * zv;
        }
        // reduce over the 4 qd-lanes (16 rows of this wave) for this col
        s  += __shfl_xor(s, 16);  s  += __shfl_xor(s, 32);
        s2 += __shfl_xor(s2, 16); s2 += __shfl_xor(s2, 32);
        if (qd == 0) {
            atomicAdd(&sum2[col], s);
            atomicAdd(&sq2[col], s2);
        }
    }
}

// ============================================================
// linear1 with FUSED batchnorm2: h3 = relu(bn(z) @ W0^T + b0)
// 64-row tiles, grid (128, 2).
// ============================================================
__launch_bounds__(256)
__global__ void k_gemm_w_norm(const float* __restrict__ z, const float* __restrict__ sum,
                              const float* __restrict__ sq, const __bf16* __restrict__ W,
                              const float* __restrict__ bias, __bf16* __restrict__ out) {
    int n0 = blockIdx.y * 128;
    int m0 = blockIdx.x * 64;
    int w = threadIdx.x >> 6, lane = threadIdx.x & 63;
    int c = lane & 15, qd = lane >> 4;
    int mw = m0 + w * 16;

    f32x4 acc[8] = {};
#pragma unroll
    for (int kc = 0; kc < 8; kc++) {
        int k0 = kc * 32 + qd * 8;
        f32x4 s0 = *(const f32x4*)(sum + k0);
        f32x4 s1 = *(const f32x4*)(sum + k0 + 4);
        f32x4 v0 = *(const f32x4*)(sq + k0);
        f32x4 v1 = *(const f32x4*)(sq + k0 + 4);
        f32x4 za = *(const f32x4*)(z + (mw + c) * L + k0);
        f32x4 zb = *(const f32x4*)(z + (mw + c) * L + k0 + 4);
        bf16x8 a;
#pragma unroll
        for (int j = 0; j < 4; j++) {
            float m  = s0[j] * (1.0f / Nrows);
            float rs = rsqrtf(v0[j] * (1.0f / Nrows) - m * m + EPS);
            a[j] = (__bf16)((za[j] - m) * rs);
        }
#pragma unroll
        for (int j = 0; j < 4; j++) {
            float m  = s1[j] * (1.0f / Nrows);
            float rs = rsqrtf(v1[j] * (1.0f / Nrows) - m * m + EPS);
            a[4 + j] = (__bf16)((zb[j] - m) * rs);
        }
#pragma unroll
        for (int nt = 0; nt < 8; nt++) {
            bf16x8 b = *(const bf16x8*)(W + (n0 + nt * 16 + c) * L + kc * 32 + qd * 8);
            acc[nt] = MFMA16(a, b, acc[nt]);
        }
    }
#pragma unroll
    for (int nt = 0; nt < 8; nt++) {
        int col = n0 + nt * 16 + c;
        float bv = bias[col];
#pragma unroll
        for (int r = 0; r < 4; r++) {
            int row = mw + 4 * qd + r;
            float v = fmaxf(acc[nt][r] + bv, 0.0f);
            out[row * L + col] = (__bf16)v;
        }
    }
}

// ============================================================
// linear2: out = relu(hin @ W1^T + b1), fp32 out; 64-row tiles, grid (128,2)
// ============================================================
__launch_bounds__(256)
__global__ void k_gemm_w(const __bf16* __restrict__ hin, const __bf16* __restrict__ W,
                         const float* __restrict__ bias, float* __restrict__ out) {
    int n0 = blockIdx.y * 128;
    int m0 = blockIdx.x * 64;
    int w = threadIdx.x >> 6, lane = threadIdx.x & 63;
    int c = lane & 15, qd = lane >> 4;
    int mw = m0 + w * 16;

    f32x4 acc[8] = {};
#pragma unroll
    for (int kc = 0; kc < 8; kc++) {
        bf16x8 a = *(const bf16x8*)(hin + (mw + c) * L + kc * 32 + qd * 8);
#pragma unroll
        for (int nt = 0; nt < 8; nt++) {
            bf16x8 b = *(const bf16x8*)(W + (n0 + nt * 16 + c) * L + kc * 32 + qd * 8);
            acc[nt] = MFMA16(a, b, acc[nt]);
        }
    }
#pragma unroll
    for (int nt = 0; nt < 8; nt++) {
        int col = n0 + nt * 16 + c;
        float bv = bias[col];
#pragma unroll
        for (int r = 0; r < 4; r++) {
            int row = mw + 4 * qd + r;
            float v = fmaxf(acc[nt][r] + bv, 0.0f);
            out[row * L + col] = v;
        }
    }
}

// ============================================================
extern "C" void kernel_launch(void* const* d_in, const int* in_sizes, int n_in,
                              void* d_out, int out_size, void* d_ws, size_t ws_size,
                              hipStream_t stream) {
    (void)in_sizes; (void)n_in; (void)out_size; (void)ws_size;
    const float* x   = (const float*)d_in[0];
    const float* Q   = (const float*)d_in[1];
    const float* K   = (const float*)d_in[2];
    const float* Vd  = (const float*)d_in[3];
    const float* Vup = (const float*)d_in[4];
    const float* W   = (const float*)d_in[5];
    const float* b   = (const float*)d_in[6];
    float* out = (float*)d_out;

    char* ws = (char*)d_ws;
    size_t off = 0;
    auto alloc = [&](size_t bytes) -> void* {
        void* p = ws + off;
        off += (bytes + 255) & ~(size_t)255;
        return p;
    };
    float*  stats = (float*)alloc(4 * 256 * sizeof(float)); // sum1,sq1,sum2,sq2
    __bf16* Bt    = (__bf16*)alloc(6 * 128 * 256 * 2);
    __bf16* VupT  = (__bf16*)alloc(2 * 256 * 128 * 2);
    __bf16* Wb    = (__bf16*)alloc(2 * 256 * 256 * 2);
    __bf16* hb    = (__bf16*)alloc((size_t)Nrows * L * 2);
    float*  hf    = (float*)alloc((size_t)Nrows * L * 4);
    __bf16* q0    = (__bf16*)alloc((size_t)Nrows * D * 2);
    __bf16* k0    = (__bf16*)alloc((size_t)Nrows * D * 2);
    __bf16* q1    = (__bf16*)alloc((size_t)Nrows * D * 2);
    __bf16* k1    = (__bf16*)alloc((size_t)Nrows * D * 2);
    __bf16* Vt    = (__bf16*)alloc((size_t)2 * 128 * Nrows * 2);
    __bf16* O     = (__bf16*)alloc((size_t)2 * Nrows * D * 2);
    float*  z     = (float*)alloc((size_t)Nrows * L * 4);
    __bf16* h3    = (__bf16*)alloc((size_t)Nrows * L * 2);

    float* sum1 = stats, *sq1 = stats + 256, *sum2 = stats + 512, *sq2 = stats + 768;

    hipMemsetAsync(stats, 0, 4 * 256 * sizeof(float), stream);
    k_cvt_params<<<1536, 256, 0, stream>>>(Q, K, Vd, Vup, W, Bt, VupT, Wb);
    k_bn_stats<<<256, 256, 0, stream>>>(x, sum1, sq1);
    k_bn_norm1<<<2048, 256, 0, stream>>>(x, sum1, sq1, hb, hf);
    k_gemm_qkv<<<dim3(128, 6), 256, 0, stream>>>(hb, Bt, q0, k0, q1, k1, Vt);
    k_flash<<<512, 256, 0, stream>>>(q0, k0, q1, k1, Vt, O);
    k_gemm_vup<<<dim3(128, 2), 256, 0, stream>>>(O, VupT, hf, z, sum2, sq2);
    k_gemm_w_norm<<<dim3(128, 2), 256, 0, stream>>>(z, sum2, sq2, Wb, b, h3);
    k_gemm_w<<<dim3(128, 2), 256, 0, stream>>>(h3, Wb + 256 * 256, b + 256, out);
}

// Round 11
// 276.193 us; speedup vs baseline: 1.4416x; 1.4416x over previous
//
#include <hip/hip_runtime.h>
#include <hip/hip_bf16.h>

// ---------- problem constants ----------
constexpr int Nrows = 8192;   // batch rows
constexpr int L     = 256;    // input_len / features
constexpr int D     = 128;    // hidden per head
constexpr float EPS = 1e-5f;

typedef __bf16 bf16x8 __attribute__((ext_vector_type(8)));
typedef __bf16 bf16x4 __attribute__((ext_vector_type(4)));
typedef float  f32x4  __attribute__((ext_vector_type(4)));

#define MFMA16(a, b, c) __builtin_amdgcn_mfma_f32_16x16x32_bf16((a), (b), (c), 0, 0, 0)

// ============================================================
// param convert+transpose (fp32 -> bf16):
//   Bt[6][128][256]: Bt[g][d][l] = P_g[l*128+d], P_g in {Q0,K0,Vd0,Q1,K1,Vd1}
//   VupT[2][256][128]: VupT[h][l][d] = Vup[h][d][l]
//   Wb[2][256][256]: straight bf16 copy of W
// ============================================================
__global__ void k_cvt_params(const float* __restrict__ Q, const float* __restrict__ K,
                             const float* __restrict__ Vd, const float* __restrict__ Vup,
                             const float* __restrict__ W,
                             __bf16* __restrict__ Bt, __bf16* __restrict__ VupT,
                             __bf16* __restrict__ Wb) {
    int i = blockIdx.x * 256 + threadIdx.x;
    if (i < 6 * 128 * 256) {
        int g = i >> 15; int r = i & 32767; int d = r >> 8; int l = r & 255;
        const float* src = (g % 3 == 0 ? Q : (g % 3 == 1 ? K : Vd)) + (g / 3) * (L * D);
        Bt[i] = (__bf16)src[l * D + d];
    } else if (i < 8 * 128 * 256) {
        int j = i - 6 * 128 * 256;               // [0, 65536)
        int h = j >> 15; int r = j & 32767; int l = r >> 7; int d = r & 127;
        VupT[j] = (__bf16)Vup[h * (D * L) + d * L + l];
    } else {
        int j = i - 8 * 128 * 256;               // [0, 131072)
        Wb[j] = (__bf16)W[j];
    }
}

// ============================================================
// batchnorm stats: per-column sum / sumsq (256 blocks x 32 rows)
// ============================================================
__global__ void k_bn_stats(const float* __restrict__ x, float* __restrict__ sum,
                           float* __restrict__ sq) {
    int col = threadIdx.x;                        // 256 columns
    int r0 = blockIdx.x * 32;                     // 256 blocks x 32 rows
    float s = 0.f, s2 = 0.f;
    for (int i = 0; i < 32; i++) {
        float v = x[(r0 + i) * L + col];
        s += v; s2 += v * v;
    }
    atomicAdd(&sum[col], s);
    atomicAdd(&sq[col], s2);
}

// ============================================================
// batchnorm normalize: bn1 emits bf16 (for GEMMs) + fp32 (residual)
// ============================================================
__global__ void k_bn_norm1(const float* __restrict__ x, const float* __restrict__ sum,
                           const float* __restrict__ sq, __bf16* __restrict__ hb,
                           float* __restrict__ hf) {
    int i = (blockIdx.x * 256 + threadIdx.x) * 4;
    int col = i & (L - 1);
    f32x4 v = *(const f32x4*)(x + i);
    bf16x4 o; f32x4 of;
#pragma unroll
    for (int j = 0; j < 4; j++) {
        float m   = sum[col + j] * (1.0f / Nrows);
        float var = sq[col + j] * (1.0f / Nrows) - m * m;
        float rs  = rsqrtf(var + EPS);
        float t = (v[j] - m) * rs;
        of[j] = t; o[j] = (__bf16)t;
    }
    *(bf16x4*)(hb + i) = o;
    *(f32x4*)(hf + i) = of;
}

// ============================================================
// QKV projection FUSED per head: 3 output matrices (q, k, v) per block
// share one A-fragment load (A-traffic 24MB -> 8MB, 768 -> 256 blocks).
// acc[3][8] = 96 VGPR + A 4 + temps ~150 < 232 (known-good (256,1) regime).
// q/k row-major [8192][128]; v TRANSPOSED Vt[head][128][8192]
// ============================================================
__launch_bounds__(256, 1)
__global__ void k_gemm_qkv(const __bf16* __restrict__ h, const __bf16* __restrict__ Bt,
                           __bf16* __restrict__ q0, __bf16* __restrict__ k0,
                           __bf16* __restrict__ q1, __bf16* __restrict__ k1,
                           __bf16* __restrict__ Vt) {
    int head = blockIdx.y;              // 0/1
    int m0 = blockIdx.x * 64;
    int w = threadIdx.x >> 6, lane = threadIdx.x & 63;
    int c = lane & 15, qd = lane >> 4;
    int mw = m0 + w * 16;
    const __bf16* B0 = Bt + (3 * head) * (128 * 256);

    f32x4 acc[3][8] = {};
#pragma unroll
    for (int kc = 0; kc < 8; kc++) {
        bf16x8 a = *(const bf16x8*)(h + (mw + c) * L + kc * 32 + qd * 8);
#pragma unroll
        for (int g = 0; g < 3; g++) {
            const __bf16* B = B0 + g * (128 * 256);
#pragma unroll
            for (int nt = 0; nt < 8; nt++) {
                bf16x8 b = *(const bf16x8*)(B + (nt * 16 + c) * L + kc * 32 + qd * 8);
                acc[g][nt] = MFMA16(a, b, acc[g][nt]);
            }
        }
    }
    __bf16* qdst = head ? q1 : q0;
    __bf16* kdst = head ? k1 : k0;
    __bf16* vt   = Vt + head * (128 * Nrows);
#pragma unroll
    for (int nt = 0; nt < 8; nt++)
#pragma unroll
        for (int r = 0; r < 4; r++) {
            int row = mw + 4 * qd + r;
            int colv = nt * 16 + c;
            qdst[row * D + colv] = (__bf16)acc[0][nt][r];
            kdst[row * D + colv] = (__bf16)acc[1][nt][r];
            vt[colv * Nrows + row] = (__bf16)acc[2][nt][r];
        }
}

// ============================================================
// Flash attention (r3/r9 verbatim: 137us, VGPR 232, no spill).
// 64 Q rows/block, 4 waves; register-double-buffered K/V prefetch.
// ============================================================
__launch_bounds__(256, 1)
__global__ void k_flash(const __bf16* __restrict__ q0, const __bf16* __restrict__ k0,
                        const __bf16* __restrict__ q1, const __bf16* __restrict__ k1,
                        const __bf16* __restrict__ Vt, __bf16* __restrict__ O) {
    int head = blockIdx.x & 1;
    int qtile = blockIdx.x >> 1;       // 0..127
    int m0 = qtile * 64;
    const __bf16* qm = head ? q1 : q0;
    const __bf16* km = head ? k1 : k0;
    const __bf16* vt = Vt + head * (128 * Nrows);
    __bf16* Og = O + head * (Nrows * D);

    int w = threadIdx.x >> 6, lane = threadIdx.x & 63;
    int c = lane & 15, qd = lane >> 4;

    __shared__ __bf16 Pb[4][64 * 56];     // stride 56 => 16B-aligned rows
    __shared__ float l_red[4][64];
    __shared__ float l_inv[64];
    __shared__ float obuf[4][64][16];

    bf16x8 aq[4][4];
#pragma unroll
    for (int mt = 0; mt < 4; mt++)
#pragma unroll
        for (int kc = 0; kc < 4; kc++)
            aq[mt][kc] = *(const bf16x8*)(qm + (m0 + mt * 16 + c) * D + kc * 32 + qd * 8);

    f32x4 oacc[4][8] = {};
    float lp[4][4] = {};
    __bf16* Pw = &Pb[w][0];

    auto loadkv = [&](bf16x8 (&kb)[2][4], bf16x8 (&vb)[8], int n0) {
        int nb = n0 + w * 32;            // this wave's key slice
#pragma unroll
        for (int nt = 0; nt < 2; nt++)
#pragma unroll
            for (int kc = 0; kc < 4; kc++)
                kb[nt][kc] = *(const bf16x8*)(km + (nb + nt * 16 + c) * D + kc * 32 + qd * 8);
#pragma unroll
        for (int dvt = 0; dvt < 8; dvt++)
            vb[dvt] = *(const bf16x8*)(vt + (dvt * 16 + c) * Nrows + nb + qd * 8);
    };

    auto compute = [&](const bf16x8 (&kb)[2][4], const bf16x8 (&vb)[8]) {
#pragma unroll
        for (int nt = 0; nt < 2; nt++) {
            f32x4 s[4] = {};
            __builtin_amdgcn_s_setprio(1);
#pragma unroll
            for (int kc = 0; kc < 4; kc++) {
#pragma unroll
                for (int mt = 0; mt < 4; mt++) s[mt] = MFMA16(aq[mt][kc], kb[nt][kc], s[mt]);
            }
            __builtin_amdgcn_s_setprio(0);
#pragma unroll
            for (int mt = 0; mt < 4; mt++)
#pragma unroll
                for (int r = 0; r < 4; r++) {
                    float e = __expf(s[mt][r]);
                    lp[mt][r] += e;
                    Pw[(mt * 16 + 4 * qd + r) * 56 + nt * 16 + c] = (__bf16)e;
                }
        }
        bf16x8 ap[4];
#pragma unroll
        for (int mt = 0; mt < 4; mt++)
            ap[mt] = *(const bf16x8*)(Pw + (mt * 16 + c) * 56 + qd * 8);
        __builtin_amdgcn_s_setprio(1);
#pragma unroll
        for (int dvt = 0; dvt < 8; dvt++) {
#pragma unroll
            for (int mt = 0; mt < 4; mt++) oacc[mt][dvt] = MFMA16(ap[mt], vb[dvt], oacc[mt][dvt]);
        }
        __builtin_amdgcn_s_setprio(0);
    };

    bf16x8 kbA[2][4], vbA[8], kbB[2][4], vbB[8];
    loadkv(kbA, vbA, 0);
    for (int n0 = 0; n0 < Nrows; n0 += 256) {
        loadkv(kbB, vbB, n0 + 128);      // prefetch tile n+1
        compute(kbA, vbA);               // consume tile n
        if (n0 + 256 < Nrows)
            loadkv(kbA, vbA, n0 + 256);  // prefetch tile n+2
        compute(kbB, vbB);               // consume tile n+1
    }

#pragma unroll
    for (int mt = 0; mt < 4; mt++)
#pragma unroll
        for (int r = 0; r < 4; r++) {
            float v = lp[mt][r];
            v += __shfl_xor(v, 1, 16);
            v += __shfl_xor(v, 2, 16);
            v += __shfl_xor(v, 4, 16);
            v += __shfl_xor(v, 8, 16);
            lp[mt][r] = v;
        }
    if (c == 0) {
#pragma unroll
        for (int mt = 0; mt < 4; mt++)
#pragma unroll
            for (int r = 0; r < 4; r++)
                l_red[w][mt * 16 + 4 * qd + r] = lp[mt][r];
    }
    __syncthreads();
    if (threadIdx.x < 64)
        l_inv[threadIdx.x] = 1.0f / (l_red[0][threadIdx.x] + l_red[1][threadIdx.x] +
                                     l_red[2][threadIdx.x] + l_red[3][threadIdx.x]);

    for (int dvt = 0; dvt < 8; dvt++) {
        __syncthreads();
#pragma unroll
        for (int mt = 0; mt < 4; mt++)
#pragma unroll
            for (int r = 0; r < 4; r++)
                obuf[w][mt * 16 + 4 * qd + r][c] = oacc[mt][dvt][r];
        __syncthreads();
        int t = threadIdx.x;
        int row = (t * 4) >> 4, col = (t * 4) & 15;
        f32x4 v = *(const f32x4*)&obuf[0][row][col];
        f32x4 v1 = *(const f32x4*)&obuf[1][row][col];
        f32x4 v2 = *(const f32x4*)&obuf[2][row][col];
        f32x4 v3 = *(const f32x4*)&obuf[3][row][col];
        float il = l_inv[row];
        bf16x4 o;
#pragma unroll
        for (int e = 0; e < 4; e++) o[e] = (__bf16)((v[e] + v1[e] + v2[e] + v3[e]) * il);
        *(bf16x4*)(Og + (m0 + row) * D + dvt * 16 + col) = o;
    }
}

// ============================================================
// z = hf + O0 @ Vup0 + O1 @ Vup1   (fp32 residual + fp32 out)
// 64-row tiles, grid (128, 2) = 256 blocks (1/CU)
// ============================================================
__launch_bounds__(256)
__global__ void k_gemm_vup(const __bf16* __restrict__ O, const __bf16* __restrict__ VupT,
                           const float* __restrict__ hf, float* __restrict__ z) {
    int n0 = blockIdx.y * 128;
    int m0 = blockIdx.x * 64;
    int w = threadIdx.x >> 6, lane = threadIdx.x & 63;
    int c = lane & 15, qd = lane >> 4;
    int mw = m0 + w * 16;

    f32x4 acc[8] = {};
#pragma unroll
    for (int kc = 0; kc < 8; kc++) {
        const __bf16* Oh = O + (kc >> 2) * (Nrows * D);
        const __bf16* Vh = VupT + (kc >> 2) * (L * D);
        int ko = (kc & 3) * 32 + qd * 8;
        bf16x8 a = *(const bf16x8*)(Oh + (mw + c) * D + ko);
#pragma unroll
        for (int nt = 0; nt < 8; nt++) {
            bf16x8 b = *(const bf16x8*)(Vh + (n0 + nt * 16 + c) * D + ko);
            acc[nt] = MFMA16(a, b, acc[nt]);
        }
    }
#pragma unroll
    for (int nt = 0; nt < 8; nt++)
#pragma unroll
        for (int r = 0; r < 4; r++) {
            int row = mw + 4 * qd + r;
            int col = n0 + nt * 16 + c;
            z[row * L + col] = acc[nt][r] + hf[row * L + col];
        }
}

// ============================================================
// linear1 with FUSED batchnorm2: h3 = relu(bn(z) @ W0^T + b0)
// 64-row tiles, grid (128, 2).
// ============================================================
__launch_bounds__(256)
__global__ void k_gemm_w_norm(const float* __restrict__ z, const float* __restrict__ sum,
                              const float* __restrict__ sq, const __bf16* __restrict__ W,
                              const float* __restrict__ bias, __bf16* __restrict__ out) {
    int n0 = blockIdx.y * 128;
    int m0 = blockIdx.x * 64;
    int w = threadIdx.x >> 6, lane = threadIdx.x & 63;
    int c = lane & 15, qd = lane >> 4;
    int mw = m0 + w * 16;

    f32x4 acc[8] = {};
#pragma unroll
    for (int kc = 0; kc < 8; kc++) {
        int k0 = kc * 32 + qd * 8;
        f32x4 s0 = *(const f32x4*)(sum + k0);
        f32x4 s1 = *(const f32x4*)(sum + k0 + 4);
        f32x4 v0 = *(const f32x4*)(sq + k0);
        f32x4 v1 = *(const f32x4*)(sq + k0 + 4);
        f32x4 za = *(const f32x4*)(z + (mw + c) * L + k0);
        f32x4 zb = *(const f32x4*)(z + (mw + c) * L + k0 + 4);
        bf16x8 a;
#pragma unroll
        for (int j = 0; j < 4; j++) {
            float m  = s0[j] * (1.0f / Nrows);
            float rs = rsqrtf(v0[j] * (1.0f / Nrows) - m * m + EPS);
            a[j] = (__bf16)((za[j] - m) * rs);
        }
#pragma unroll
        for (int j = 0; j < 4; j++) {
            float m  = s1[j] * (1.0f / Nrows);
            float rs = rsqrtf(v1[j] * (1.0f / Nrows) - m * m + EPS);
            a[4 + j] = (__bf16)((zb[j] - m) * rs);
        }
#pragma unroll
        for (int nt = 0; nt < 8; nt++) {
            bf16x8 b = *(const bf16x8*)(W + (n0 + nt * 16 + c) * L + kc * 32 + qd * 8);
            acc[nt] = MFMA16(a, b, acc[nt]);
        }
    }
#pragma unroll
    for (int nt = 0; nt < 8; nt++) {
        int col = n0 + nt * 16 + c;
        float bv = bias[col];
#pragma unroll
        for (int r = 0; r < 4; r++) {
            int row = mw + 4 * qd + r;
            float v = fmaxf(acc[nt][r] + bv, 0.0f);
            out[row * L + col] = (__bf16)v;
        }
    }
}

// ============================================================
// linear2: out = relu(hin @ W1^T + b1), fp32 out; 64-row tiles, grid (128,2)
// ============================================================
__launch_bounds__(256)
__global__ void k_gemm_w(const __bf16* __restrict__ hin, const __bf16* __restrict__ W,
                         const float* __restrict__ bias, float* __restrict__ out) {
    int n0 = blockIdx.y * 128;
    int m0 = blockIdx.x * 64;
    int w = threadIdx.x >> 6, lane = threadIdx.x & 63;
    int c = lane & 15, qd = lane >> 4;
    int mw = m0 + w * 16;

    f32x4 acc[8] = {};
#pragma unroll
    for (int kc = 0; kc < 8; kc++) {
        bf16x8 a = *(const bf16x8*)(hin + (mw + c) * L + kc * 32 + qd * 8);
#pragma unroll
        for (int nt = 0; nt < 8; nt++) {
            bf16x8 b = *(const bf16x8*)(W + (n0 + nt * 16 + c) * L + kc * 32 + qd * 8);
            acc[nt] = MFMA16(a, b, acc[nt]);
        }
    }
#pragma unroll
    for (int nt = 0; nt < 8; nt++) {
        int col = n0 + nt * 16 + c;
        float bv = bias[col];
#pragma unroll
        for (int r = 0; r < 4; r++) {
            int row = mw + 4 * qd + r;
            float v = fmaxf(acc[nt][r] + bv, 0.0f);
            out[row * L + col] = v;
        }
    }
}

// ============================================================
extern "C" void kernel_launch(void* const* d_in, const int* in_sizes, int n_in,
                              void* d_out, int out_size, void* d_ws, size_t ws_size,
                              hipStream_t stream) {
    (void)in_sizes; (void)n_in; (void)out_size; (void)ws_size;
    const float* x   = (const float*)d_in[0];
    const float* Q   = (const float*)d_in[1];
    const float* K   = (const float*)d_in[2];
    const float* Vd  = (const float*)d_in[3];
    const float* Vup = (const float*)d_in[4];
    const float* W   = (const float*)d_in[5];
    const float* b   = (const float*)d_in[6];
    float* out = (float*)d_out;

    char* ws = (char*)d_ws;
    size_t off = 0;
    auto alloc = [&](size_t bytes) -> void* {
        void* p = ws + off;
        off += (bytes + 255) & ~(size_t)255;
        return p;
    };
    float*  stats = (float*)alloc(4 * 256 * sizeof(float)); // sum1,sq1,sum2,sq2
    __bf16* Bt    = (__bf16*)alloc(6 * 128 * 256 * 2);
    __bf16* VupT  = (__bf16*)alloc(2 * 256 * 128 * 2);
    __bf16* Wb    = (__bf16*)alloc(2 * 256 * 256 * 2);
    __bf16* hb    = (__bf16*)alloc((size_t)Nrows * L * 2);
    float*  hf    = (float*)alloc((size_t)Nrows * L * 4);
    __bf16* q0    = (__bf16*)alloc((size_t)Nrows * D * 2);
    __bf16* k0    = (__bf16*)alloc((size_t)Nrows * D * 2);
    __bf16* q1    = (__bf16*)alloc((size_t)Nrows * D * 2);
    __bf16* k1    = (__bf16*)alloc((size_t)Nrows * D * 2);
    __bf16* Vt    = (__bf16*)alloc((size_t)2 * 128 * Nrows * 2);
    __bf16* O     = (__bf16*)alloc((size_t)2 * Nrows * D * 2);
    float*  z     = (float*)alloc((size_t)Nrows * L * 4);
    __bf16* h3    = (__bf16*)alloc((size_t)Nrows * L * 2);

    float* sum1 = stats, *sq1 = stats + 256, *sum2 = stats + 512, *sq2 = stats + 768;

    hipMemsetAsync(stats, 0, 4 * 256 * sizeof(float), stream);
    k_cvt_params<<<1536, 256, 0, stream>>>(Q, K, Vd, Vup, W, Bt, VupT, Wb);
    k_bn_stats<<<256, 256, 0, stream>>>(x, sum1, sq1);
    k_bn_norm1<<<2048, 256, 0, stream>>>(x, sum1, sq1, hb, hf);
    k_gemm_qkv<<<dim3(128, 2), 256, 0, stream>>>(hb, Bt, q0, k0, q1, k1, Vt);
    k_flash<<<256, 256, 0, stream>>>(q0, k0, q1, k1, Vt, O);
    k_gemm_vup<<<dim3(128, 2), 256, 0, stream>>>(O, VupT, hf, z);
    k_bn_stats<<<256, 256, 0, stream>>>(z, sum2, sq2);
    k_gemm_w_norm<<<dim3(128, 2), 256, 0, stream>>>(z, sum2, sq2, Wb, b, h3);
    k_gemm_w<<<dim3(128, 2), 256, 0, stream>>>(h3, Wb + 256 * 256, b + 256, out);
}